// Round 6
// baseline (418.864 us; speedup 1.0000x reference)
//
#include <hip/hip_runtime.h>
#include <math.h>

#define NUM_EMB 512
#define EMB_DIM 64
#define S_SPATIAL 32768   // 32*32*32
#define BATCH 4
#define NVEC (BATCH * S_SPATIAL)  // 131072 vectors
#define NCHUNK 4
#define KCHUNK (NUM_EMB / NCHUNK) // 128 codes per chunk

// Workspace layout (d_ws):
//   0      : double loss_accum
//   256    : float  cbnorm[512]            (ends 2304)
//   4096   : float  best[NCHUNK][NVEC]     (2 MB)
//   4096+2M: int    bk  [NCHUNK][NVEC]     (2 MB)
#define WS_BEST_OFF 4096
#define WS_BK_OFF   (4096 + NCHUNK * NVEC * 4)
#define WS_NEEDED   (4096 + 2 * NCHUNK * NVEC * 4)

// ---------------------------------------------------------------------------
__global__ void vq_prep(const float* __restrict__ cb,
                        float* __restrict__ cbnorm,
                        double* __restrict__ loss_accum) {
    int k = blockIdx.x * blockDim.x + threadIdx.x;
    if (k == 0) *loss_accum = 0.0;
    if (k < NUM_EMB) {
        const float* e = cb + k * EMB_DIM;
        float s = 0.f;
        #pragma unroll
        for (int c = 0; c < EMB_DIM; ++c)
            s = __fadd_rn(s, __fmul_rn(e[c], e[c]));
        cbnorm[k] = s;
    }
}

// ---------------------------------------------------------------------------
// Pass 1 (split-K): block = 256 vectors x one chunk of 128 codes.
// Grid = 512 vector-groups * 4 chunks = 2048 blocks -> 8 blocks/CU ->
// 8 waves/SIMD (vs 2 before): hides the SGPR-serialized codebook s_loads.
// FP order bit-identical to the R2 passing kernel.
// ---------------------------------------------------------------------------
__global__ __launch_bounds__(256, 8) void vq_part(
        const float* __restrict__ in,
        const float* __restrict__ cb,
        const float* __restrict__ cbnorm,
        float* __restrict__ best,          // [NCHUNK][NVEC]
        int*   __restrict__ bk) {          // [NCHUNK][NVEC]
    const int vg    = blockIdx.x & 511;
    const int chunk = blockIdx.x >> 9;
    const int n = vg * 256 + threadIdx.x;
    const int b = n >> 15;
    const int s = n & (S_SPATIAL - 1);

    const float* xp = in + (size_t)b * EMB_DIM * S_SPATIAL + s;
    const size_t S = (size_t)S_SPATIAL;

#define LDX(i) const float4 x##i = make_float4(xp[(4*i+0)*S], xp[(4*i+1)*S], \
                                               xp[(4*i+2)*S], xp[(4*i+3)*S])
    LDX(0);  LDX(1);  LDX(2);  LDX(3);  LDX(4);  LDX(5);  LDX(6);  LDX(7);
    LDX(8);  LDX(9);  LDX(10); LDX(11); LDX(12); LDX(13); LDX(14); LDX(15);
#undef LDX

    float xn = 0.f;
#define XN(i) xn = __fadd_rn(xn, __fmul_rn(x##i.x, x##i.x)); \
              xn = __fadd_rn(xn, __fmul_rn(x##i.y, x##i.y)); \
              xn = __fadd_rn(xn, __fmul_rn(x##i.z, x##i.z)); \
              xn = __fadd_rn(xn, __fmul_rn(x##i.w, x##i.w))
    XN(0);  XN(1);  XN(2);  XN(3);  XN(4);  XN(5);  XN(6);  XN(7);
    XN(8);  XN(9);  XN(10); XN(11); XN(12); XN(13); XN(14); XN(15);
#undef XN

    const float* cbc = cb + (size_t)chunk * KCHUNK * EMB_DIM;
    const float* cbn = cbnorm + chunk * KCHUNK;

    float bestd = INFINITY;
    int bestk = 0;
    for (int k = 0; k < KCHUNK; ++k) {
        const float4* ev = (const float4*)(cbc + (size_t)k * EMB_DIM); // uniform
        float a0 = 0.f, a1 = 0.f, a2 = 0.f, a3 = 0.f;
#define DOT(i) { const float4 e = ev[i];            \
                 a0 = fmaf(x##i.x, e.x, a0);        \
                 a1 = fmaf(x##i.y, e.y, a1);        \
                 a2 = fmaf(x##i.z, e.z, a2);        \
                 a3 = fmaf(x##i.w, e.w, a3); }
        DOT(0);  DOT(1);  DOT(2);  DOT(3);  DOT(4);  DOT(5);  DOT(6);  DOT(7);
        DOT(8);  DOT(9);  DOT(10); DOT(11); DOT(12); DOT(13); DOT(14); DOT(15);
#undef DOT
        float dot = __fadd_rn(__fadd_rn(a0, a1), __fadd_rn(a2, a3));
        float d = __fsub_rn(__fadd_rn(xn, cbn[k]),
                            __fmul_rn(2.f, dot));
        if (d < bestd) { bestd = d; bestk = k; }
    }
    best[chunk * NVEC + n] = bestd;
    bk  [chunk * NVEC + n] = chunk * KCHUNK + bestk;
}

// ---------------------------------------------------------------------------
// Pass 2: combine the 4 chunk-argmins (ascending chunk order + strict '<'
// == global first-index argmin), gather the winning code, write output,
// accumulate loss. c-tiled: thread = (vector, 16-channel tile) -> 2048 blocks.
// ---------------------------------------------------------------------------
__global__ __launch_bounds__(256) void vq_fin(
        const float* __restrict__ in,
        const float* __restrict__ cb,
        const float* __restrict__ best,
        const int*   __restrict__ bk,
        float* __restrict__ outq,
        double* __restrict__ loss_accum) {
    const int vg = blockIdx.x & 511;
    const int ct = blockIdx.x >> 9;          // channel tile: 16 channels
    const int n = vg * 256 + threadIdx.x;
    const int b = n >> 15;
    const int s = n & (S_SPATIAL - 1);

    float bd = best[n];
    int kk = bk[n];
    #pragma unroll
    for (int c = 1; c < NCHUNK; ++c) {
        float d = best[c * NVEC + n];
        if (d < bd) { bd = d; kk = bk[c * NVEC + n]; }
    }

    const size_t S = (size_t)S_SPATIAL;
    const float* xp = in + (size_t)b * EMB_DIM * S_SPATIAL + s + (size_t)(ct * 16) * S;
    float* op = outq + (size_t)b * EMB_DIM * S_SPATIAL + s + (size_t)(ct * 16) * S;
    const float4* q = (const float4*)(cb + (size_t)kk * EMB_DIM + ct * 16);

    float lsum = 0.f;
    #pragma unroll
    for (int i = 0; i < 4; ++i) {
        const float4 qv = q[i];
        float x0 = xp[(4*i+0)*S], x1 = xp[(4*i+1)*S];
        float x2 = xp[(4*i+2)*S], x3 = xp[(4*i+3)*S];
        op[(4*i+0)*S] = qv.x; op[(4*i+1)*S] = qv.y;
        op[(4*i+2)*S] = qv.z; op[(4*i+3)*S] = qv.w;
        float d0 = __fsub_rn(qv.x, x0);
        float d1 = __fsub_rn(qv.y, x1);
        float d2 = __fsub_rn(qv.z, x2);
        float d3 = __fsub_rn(qv.w, x3);
        lsum = __fadd_rn(lsum, __fmul_rn(d0, d0));
        lsum = __fadd_rn(lsum, __fmul_rn(d1, d1));
        lsum = __fadd_rn(lsum, __fmul_rn(d2, d2));
        lsum = __fadd_rn(lsum, __fmul_rn(d3, d3));
    }

    // wave reduce in double -> per-block atomic
    double ls = (double)lsum;
    #pragma unroll
    for (int off = 32; off > 0; off >>= 1)
        ls += __shfl_down(ls, off, 64);
    __shared__ double wsum[4];
    const int lane = threadIdx.x & 63;
    const int wid  = threadIdx.x >> 6;
    if (lane == 0) wsum[wid] = ls;
    __syncthreads();
    if (threadIdx.x == 0) {
        double t = ((wsum[0] + wsum[1]) + (wsum[2] + wsum[3]));
        atomicAdd(loss_accum, t);
    }
}

// ---------------------------------------------------------------------------
// Fallback single-kernel (R2 proven path) if ws is too small for partials.
// ---------------------------------------------------------------------------
__global__ __launch_bounds__(256, 2) void vq_main_single(
        const float* __restrict__ in,
        const float* __restrict__ cb,
        const float* __restrict__ cbnorm,
        float* __restrict__ outq,
        double* __restrict__ loss_accum) {
    const int n = blockIdx.x * 256 + threadIdx.x;
    const int b = n >> 15;
    const int s = n & (S_SPATIAL - 1);
    const float* xp = in + (size_t)b * EMB_DIM * S_SPATIAL + s;
    const size_t S = (size_t)S_SPATIAL;
#define LDX(i) const float4 x##i = make_float4(xp[(4*i+0)*S], xp[(4*i+1)*S], \
                                               xp[(4*i+2)*S], xp[(4*i+3)*S])
    LDX(0);  LDX(1);  LDX(2);  LDX(3);  LDX(4);  LDX(5);  LDX(6);  LDX(7);
    LDX(8);  LDX(9);  LDX(10); LDX(11); LDX(12); LDX(13); LDX(14); LDX(15);
#undef LDX
    float xn = 0.f;
#define XN(i) xn = __fadd_rn(xn, __fmul_rn(x##i.x, x##i.x)); \
              xn = __fadd_rn(xn, __fmul_rn(x##i.y, x##i.y)); \
              xn = __fadd_rn(xn, __fmul_rn(x##i.z, x##i.z)); \
              xn = __fadd_rn(xn, __fmul_rn(x##i.w, x##i.w))
    XN(0);  XN(1);  XN(2);  XN(3);  XN(4);  XN(5);  XN(6);  XN(7);
    XN(8);  XN(9);  XN(10); XN(11); XN(12); XN(13); XN(14); XN(15);
#undef XN
    float bestd = INFINITY;
    int bestk = 0;
    for (int k = 0; k < NUM_EMB; ++k) {
        const float4* ev = (const float4*)(cb + (size_t)k * EMB_DIM);
        float a0 = 0.f, a1 = 0.f, a2 = 0.f, a3 = 0.f;
#define DOT(i) { const float4 e = ev[i];            \
                 a0 = fmaf(x##i.x, e.x, a0);        \
                 a1 = fmaf(x##i.y, e.y, a1);        \
                 a2 = fmaf(x##i.z, e.z, a2);        \
                 a3 = fmaf(x##i.w, e.w, a3); }
        DOT(0);  DOT(1);  DOT(2);  DOT(3);  DOT(4);  DOT(5);  DOT(6);  DOT(7);
        DOT(8);  DOT(9);  DOT(10); DOT(11); DOT(12); DOT(13); DOT(14); DOT(15);
#undef DOT
        float dot = __fadd_rn(__fadd_rn(a0, a1), __fadd_rn(a2, a3));
        float d = __fsub_rn(__fadd_rn(xn, cbnorm[k]),
                            __fmul_rn(2.f, dot));
        if (d < bestd) { bestd = d; bestk = k; }
    }
    const float4* q = (const float4*)(cb + (size_t)bestk * EMB_DIM);
    float* op = outq + (size_t)b * EMB_DIM * S_SPATIAL + s;
    float lsum = 0.f;
#define OUTC(i) { const float4 qv = q[i];                                   \
                  op[(4*i+0)*S] = qv.x; op[(4*i+1)*S] = qv.y;               \
                  op[(4*i+2)*S] = qv.z; op[(4*i+3)*S] = qv.w;               \
                  float d0 = __fsub_rn(qv.x, x##i.x);                       \
                  float d1 = __fsub_rn(qv.y, x##i.y);                       \
                  float d2 = __fsub_rn(qv.z, x##i.z);                       \
                  float d3 = __fsub_rn(qv.w, x##i.w);                       \
                  lsum = __fadd_rn(lsum, __fmul_rn(d0, d0));                \
                  lsum = __fadd_rn(lsum, __fmul_rn(d1, d1));                \
                  lsum = __fadd_rn(lsum, __fmul_rn(d2, d2));                \
                  lsum = __fadd_rn(lsum, __fmul_rn(d3, d3)); }
    OUTC(0);  OUTC(1);  OUTC(2);  OUTC(3);  OUTC(4);  OUTC(5);  OUTC(6);  OUTC(7);
    OUTC(8);  OUTC(9);  OUTC(10); OUTC(11); OUTC(12); OUTC(13); OUTC(14); OUTC(15);
#undef OUTC
    double ls = (double)lsum;
    #pragma unroll
    for (int off = 32; off > 0; off >>= 1)
        ls += __shfl_down(ls, off, 64);
    __shared__ double wsum[4];
    const int lane = threadIdx.x & 63;
    const int wid  = threadIdx.x >> 6;
    if (lane == 0) wsum[wid] = ls;
    __syncthreads();
    if (threadIdx.x == 0)
        atomicAdd(loss_accum, (wsum[0] + wsum[1]) + (wsum[2] + wsum[3]));
}

// ---------------------------------------------------------------------------
__global__ void vq_final(const double* __restrict__ loss_accum,
                         float* __restrict__ out0) {
    double m = *loss_accum / (double)((long long)NVEC * EMB_DIM);
    float mf = (float)m;
    out0[0] = __fadd_rn(mf, __fmul_rn(0.25f, mf));
}

extern "C" void kernel_launch(void* const* d_in, const int* in_sizes, int n_in,
                              void* d_out, int out_size, void* d_ws, size_t ws_size,
                              hipStream_t stream) {
    const float* in = (const float*)d_in[0];   // [4, 64, 32, 32, 32]
    const float* cb = (const float*)d_in[1];   // [512, 64]
    float* out = (float*)d_out;                // [0]=loss, [1..]=quantized

    double* loss_accum = (double*)d_ws;
    float* cbnorm = (float*)((char*)d_ws + 256);

    vq_prep<<<4, 128, 0, stream>>>(cb, cbnorm, loss_accum);

    if (ws_size >= (size_t)WS_NEEDED) {
        float* best = (float*)((char*)d_ws + WS_BEST_OFF);
        int*   bkp  = (int*)  ((char*)d_ws + WS_BK_OFF);
        vq_part<<<512 * NCHUNK, 256, 0, stream>>>(in, cb, cbnorm, best, bkp);
        vq_fin <<<512 * 4,      256, 0, stream>>>(in, cb, best, bkp, out + 1,
                                                  loss_accum);
    } else {
        vq_main_single<<<NVEC / 256, 256, 0, stream>>>(in, cb, cbnorm, out + 1,
                                                       loss_accum);
    }
    vq_final<<<1, 1, 0, stream>>>(loss_accum, out);
}

// Round 7
// 262.654 us; speedup vs baseline: 1.5947x; 1.5947x over previous
//
#include <hip/hip_runtime.h>
#include <math.h>

#define NUM_EMB 512
#define EMB_DIM 64
#define S_SPATIAL 32768   // 32*32*32
#define BATCH 4
#define NVEC (BATCH * S_SPATIAL)  // 131072 vectors

// Workspace layout (d_ws):
//   0      : double loss_accum
//   256    : float  cbnorm[512]

// ---------------------------------------------------------------------------
__global__ void vq_prep(const float* __restrict__ cb,
                        float* __restrict__ cbnorm,
                        double* __restrict__ loss_accum) {
    int k = blockIdx.x * blockDim.x + threadIdx.x;
    if (k == 0) *loss_accum = 0.0;
    if (k < NUM_EMB) {
        const float* e = cb + k * EMB_DIM;
        float s = 0.f;
        #pragma unroll
        for (int c = 0; c < EMB_DIM; ++c)
            s = __fadd_rn(s, __fmul_rn(e[c], e[c]));
        cbnorm[k] = s;
    }
}

// ---------------------------------------------------------------------------
// One thread per vector. x lives in 16 named float4s; each component is
// pinned with an empty inline-asm "+v" barrier right after the load. This
// makes the values opaque (not pure loads), so LLVM cannot sink/rematerialize
// the x loads into the 512-iteration k-loop (R2 evidence: VGPR=56 < 64
// needed for x, no spill traffic -> loads were sunk; hot loop was
// VMEM-bound at 20% per-wave duty). Codebook row address is wave-uniform.
// FP order bit-identical to the R2 passing kernel.
// ---------------------------------------------------------------------------
__global__ __launch_bounds__(256, 2) void vq_main(
        const float* __restrict__ in,
        const float* __restrict__ cb,
        const float* __restrict__ cbnorm,
        float* __restrict__ outq,          // d_out + 1 (quantized, [B,C,D,H,W])
        double* __restrict__ loss_accum) {
    const int n = blockIdx.x * 256 + threadIdx.x;   // vector id, < NVEC exactly
    const int b = n >> 15;          // n / S_SPATIAL
    const int s = n & (S_SPATIAL - 1);

    const float* xp = in + (size_t)b * EMB_DIM * S_SPATIAL + s;
    const size_t S = (size_t)S_SPATIAL;

    // ---- load x into 16 named float4 registers (coalesced across lanes),
    //      then PIN each component in a VGPR via empty asm ----
#define LDX(i) float4 x##i = make_float4(xp[(4*i+0)*S], xp[(4*i+1)*S], \
                                         xp[(4*i+2)*S], xp[(4*i+3)*S]); \
               asm volatile("" : "+v"(x##i.x), "+v"(x##i.y),            \
                                 "+v"(x##i.z), "+v"(x##i.w))
    LDX(0);  LDX(1);  LDX(2);  LDX(3);  LDX(4);  LDX(5);  LDX(6);  LDX(7);
    LDX(8);  LDX(9);  LDX(10); LDX(11); LDX(12); LDX(13); LDX(14); LDX(15);
#undef LDX

    // ---- xnorm, sequential c order (matches jnp.sum(flat*flat, axis=1)) ----
    float xn = 0.f;
#define XN(i) xn = __fadd_rn(xn, __fmul_rn(x##i.x, x##i.x)); \
              xn = __fadd_rn(xn, __fmul_rn(x##i.y, x##i.y)); \
              xn = __fadd_rn(xn, __fmul_rn(x##i.z, x##i.z)); \
              xn = __fadd_rn(xn, __fmul_rn(x##i.w, x##i.w))
    XN(0);  XN(1);  XN(2);  XN(3);  XN(4);  XN(5);  XN(6);  XN(7);
    XN(8);  XN(9);  XN(10); XN(11); XN(12); XN(13); XN(14); XN(15);
#undef XN

    // ---- argmin over 512 codes ----
    float best = INFINITY;
    int bestk = 0;
    for (int k = 0; k < NUM_EMB; ++k) {
        const float4* ev = (const float4*)(cb + (size_t)k * EMB_DIM); // uniform
        float a0 = 0.f, a1 = 0.f, a2 = 0.f, a3 = 0.f;
#define DOT(i) { const float4 e = ev[i];            \
                 a0 = fmaf(x##i.x, e.x, a0);        \
                 a1 = fmaf(x##i.y, e.y, a1);        \
                 a2 = fmaf(x##i.z, e.z, a2);        \
                 a3 = fmaf(x##i.w, e.w, a3); }
        DOT(0);  DOT(1);  DOT(2);  DOT(3);  DOT(4);  DOT(5);  DOT(6);  DOT(7);
        DOT(8);  DOT(9);  DOT(10); DOT(11); DOT(12); DOT(13); DOT(14); DOT(15);
#undef DOT
        float dot = __fadd_rn(__fadd_rn(a0, a1), __fadd_rn(a2, a3));
        float d = __fsub_rn(__fadd_rn(xn, cbnorm[k]),
                            __fmul_rn(2.f, dot));
        if (d < best) { best = d; bestk = k; }
    }

    // ---- gather winning code, write output, loss partial ----
    const float4* q = (const float4*)(cb + (size_t)bestk * EMB_DIM);
    float* op = outq + (size_t)b * EMB_DIM * S_SPATIAL + s;
    float lsum = 0.f;
#define OUTC(i) { const float4 qv = q[i];                                   \
                  op[(4*i+0)*S] = qv.x; op[(4*i+1)*S] = qv.y;               \
                  op[(4*i+2)*S] = qv.z; op[(4*i+3)*S] = qv.w;               \
                  float d0 = __fsub_rn(qv.x, x##i.x);                       \
                  float d1 = __fsub_rn(qv.y, x##i.y);                       \
                  float d2 = __fsub_rn(qv.z, x##i.z);                       \
                  float d3 = __fsub_rn(qv.w, x##i.w);                       \
                  lsum = __fadd_rn(lsum, __fmul_rn(d0, d0));                \
                  lsum = __fadd_rn(lsum, __fmul_rn(d1, d1));                \
                  lsum = __fadd_rn(lsum, __fmul_rn(d2, d2));                \
                  lsum = __fadd_rn(lsum, __fmul_rn(d3, d3)); }
    OUTC(0);  OUTC(1);  OUTC(2);  OUTC(3);  OUTC(4);  OUTC(5);  OUTC(6);  OUTC(7);
    OUTC(8);  OUTC(9);  OUTC(10); OUTC(11); OUTC(12); OUTC(13); OUTC(14); OUTC(15);
#undef OUTC

    // ---- block reduction of lsum -> one double atomicAdd per block ----
    double ls = (double)lsum;
    #pragma unroll
    for (int off = 32; off > 0; off >>= 1)
        ls += __shfl_down(ls, off, 64);
    __shared__ double wsum[4];
    const int lane = threadIdx.x & 63;
    const int wid  = threadIdx.x >> 6;
    if (lane == 0) wsum[wid] = ls;
    __syncthreads();
    if (threadIdx.x == 0) {
        double t = ((wsum[0] + wsum[1]) + (wsum[2] + wsum[3]));
        atomicAdd(loss_accum, t);
    }
}

// ---------------------------------------------------------------------------
__global__ void vq_final(const double* __restrict__ loss_accum,
                         float* __restrict__ out0) {
    double m = *loss_accum / (double)((long long)NVEC * EMB_DIM);
    float mf = (float)m;
    out0[0] = __fadd_rn(mf, __fmul_rn(0.25f, mf));
}

extern "C" void kernel_launch(void* const* d_in, const int* in_sizes, int n_in,
                              void* d_out, int out_size, void* d_ws, size_t ws_size,
                              hipStream_t stream) {
    const float* in = (const float*)d_in[0];   // [4, 64, 32, 32, 32]
    const float* cb = (const float*)d_in[1];   // [512, 64]
    float* out = (float*)d_out;                // [0]=loss, [1..]=quantized

    double* loss_accum = (double*)d_ws;
    float* cbnorm = (float*)((char*)d_ws + 256);

    vq_prep<<<4, 128, 0, stream>>>(cb, cbnorm, loss_accum);
    vq_main<<<NVEC / 256, 256, 0, stream>>>(in, cb, cbnorm, out + 1, loss_accum);
    vq_final<<<1, 1, 0, stream>>>(loss_accum, out);
}

// Round 9
// 209.413 us; speedup vs baseline: 2.0002x; 1.2542x over previous
//
#include <hip/hip_runtime.h>
#include <math.h>

#define NUM_EMB 512
#define EMB_DIM 64
#define S_SPATIAL 32768   // 32*32*32
#define BATCH 4
#define NVEC (BATCH * S_SPATIAL)  // 131072 vectors
#define NCHUNK 4
#define KCHUNK (NUM_EMB / NCHUNK) // 128 codes per chunk

// Workspace layout (d_ws):
//   0      : double loss_accum
//   256    : float  cbnorm[512]            (ends 2304)
//   4096   : float  best[NCHUNK][NVEC]     (2 MB)
//   4096+2M: int    bk  [NCHUNK][NVEC]     (2 MB)
#define WS_BEST_OFF 4096
#define WS_BK_OFF   (4096 + NCHUNK * NVEC * 4)
#define WS_NEEDED   (4096 + 2 * NCHUNK * NVEC * 4)

// ---------------------------------------------------------------------------
__global__ void vq_prep(const float* __restrict__ cb,
                        float* __restrict__ cbnorm,
                        double* __restrict__ loss_accum) {
    int k = blockIdx.x * blockDim.x + threadIdx.x;
    if (k == 0) *loss_accum = 0.0;
    if (k < NUM_EMB) {
        const float* e = cb + k * EMB_DIM;
        float s = 0.f;
        #pragma unroll
        for (int c = 0; c < EMB_DIM; ++c)
            s = __fadd_rn(s, __fmul_rn(e[c], e[c]));
        cbnorm[k] = s;
    }
}

// ---------------------------------------------------------------------------
// Pass 1 (split-K): block = 256 vectors x one chunk of 128 codes.
// Grid = 2048 blocks. R6 proved occupancy jumps to ~81% here; R6's failure
// was ONLY the (256,8) launch-bounds VGPR=32 cap causing scratch thrash
// (WRITE 45MB vs 4.2MB real). (256,2) keeps the natural ~56-VGPR allocation
// (<=64 -> HW still fits 8 blocks/CU) with zero spill. 8 waves/SIMD x ~20%
// per-wave duty (serialized codebook s_load latency) -> VALU pipe saturates.
// FP order bit-identical to the R2/R6 passing kernels.
// ---------------------------------------------------------------------------
__global__ __launch_bounds__(256, 2) void vq_part(
        const float* __restrict__ in,
        const float* __restrict__ cb,
        const float* __restrict__ cbnorm,
        float* __restrict__ best,          // [NCHUNK][NVEC]
        int*   __restrict__ bk) {          // [NCHUNK][NVEC]
    const int vg    = blockIdx.x & 511;
    const int chunk = blockIdx.x >> 9;
    const int n = vg * 256 + threadIdx.x;
    const int b = n >> 15;
    const int s = n & (S_SPATIAL - 1);

    const float* xp = in + (size_t)b * EMB_DIM * S_SPATIAL + s;
    const size_t S = (size_t)S_SPATIAL;

#define LDX(i) const float4 x##i = make_float4(xp[(4*i+0)*S], xp[(4*i+1)*S], \
                                               xp[(4*i+2)*S], xp[(4*i+3)*S])
    LDX(0);  LDX(1);  LDX(2);  LDX(3);  LDX(4);  LDX(5);  LDX(6);  LDX(7);
    LDX(8);  LDX(9);  LDX(10); LDX(11); LDX(12); LDX(13); LDX(14); LDX(15);
#undef LDX

    float xn = 0.f;
#define XN(i) xn = __fadd_rn(xn, __fmul_rn(x##i.x, x##i.x)); \
              xn = __fadd_rn(xn, __fmul_rn(x##i.y, x##i.y)); \
              xn = __fadd_rn(xn, __fmul_rn(x##i.z, x##i.z)); \
              xn = __fadd_rn(xn, __fmul_rn(x##i.w, x##i.w))
    XN(0);  XN(1);  XN(2);  XN(3);  XN(4);  XN(5);  XN(6);  XN(7);
    XN(8);  XN(9);  XN(10); XN(11); XN(12); XN(13); XN(14); XN(15);
#undef XN

    const float* cbc = cb + (size_t)chunk * KCHUNK * EMB_DIM;
    const float* cbn = cbnorm + chunk * KCHUNK;

    float bestd = INFINITY;
    int bestk = 0;
    for (int k = 0; k < KCHUNK; ++k) {
        const float4* ev = (const float4*)(cbc + (size_t)k * EMB_DIM); // uniform
        float a0 = 0.f, a1 = 0.f, a2 = 0.f, a3 = 0.f;
#define DOT(i) { const float4 e = ev[i];            \
                 a0 = fmaf(x##i.x, e.x, a0);        \
                 a1 = fmaf(x##i.y, e.y, a1);        \
                 a2 = fmaf(x##i.z, e.z, a2);        \
                 a3 = fmaf(x##i.w, e.w, a3); }
        DOT(0);  DOT(1);  DOT(2);  DOT(3);  DOT(4);  DOT(5);  DOT(6);  DOT(7);
        DOT(8);  DOT(9);  DOT(10); DOT(11); DOT(12); DOT(13); DOT(14); DOT(15);
#undef DOT
        float dot = __fadd_rn(__fadd_rn(a0, a1), __fadd_rn(a2, a3));
        float d = __fsub_rn(__fadd_rn(xn, cbn[k]),
                            __fmul_rn(2.f, dot));
        if (d < bestd) { bestd = d; bestk = k; }
    }
    best[chunk * NVEC + n] = bestd;
    bk  [chunk * NVEC + n] = chunk * KCHUNK + bestk;
}

// ---------------------------------------------------------------------------
// Pass 2: combine the 4 chunk-argmins (ascending chunk order + strict '<'
// == global first-index argmin), gather the winning code, write output,
// accumulate loss. c-tiled: thread = (vector, 16-channel tile) -> 2048 blocks.
// ---------------------------------------------------------------------------
__global__ __launch_bounds__(256) void vq_fin(
        const float* __restrict__ in,
        const float* __restrict__ cb,
        const float* __restrict__ best,
        const int*   __restrict__ bk,
        float* __restrict__ outq,
        double* __restrict__ loss_accum) {
    const int vg = blockIdx.x & 511;
    const int ct = blockIdx.x >> 9;          // channel tile: 16 channels
    const int n = vg * 256 + threadIdx.x;
    const int b = n >> 15;
    const int s = n & (S_SPATIAL - 1);

    float bd = best[n];
    int kk = bk[n];
    #pragma unroll
    for (int c = 1; c < NCHUNK; ++c) {
        float d = best[c * NVEC + n];
        if (d < bd) { bd = d; kk = bk[c * NVEC + n]; }
    }

    const size_t S = (size_t)S_SPATIAL;
    const float* xp = in + (size_t)b * EMB_DIM * S_SPATIAL + s + (size_t)(ct * 16) * S;
    float* op = outq + (size_t)b * EMB_DIM * S_SPATIAL + s + (size_t)(ct * 16) * S;
    const float4* q = (const float4*)(cb + (size_t)kk * EMB_DIM + ct * 16);

    float lsum = 0.f;
    #pragma unroll
    for (int i = 0; i < 4; ++i) {
        const float4 qv = q[i];
        float x0 = xp[(4*i+0)*S], x1 = xp[(4*i+1)*S];
        float x2 = xp[(4*i+2)*S], x3 = xp[(4*i+3)*S];
        op[(4*i+0)*S] = qv.x; op[(4*i+1)*S] = qv.y;
        op[(4*i+2)*S] = qv.z; op[(4*i+3)*S] = qv.w;
        float d0 = __fsub_rn(qv.x, x0);
        float d1 = __fsub_rn(qv.y, x1);
        float d2 = __fsub_rn(qv.z, x2);
        float d3 = __fsub_rn(qv.w, x3);
        lsum = __fadd_rn(lsum, __fmul_rn(d0, d0));
        lsum = __fadd_rn(lsum, __fmul_rn(d1, d1));
        lsum = __fadd_rn(lsum, __fmul_rn(d2, d2));
        lsum = __fadd_rn(lsum, __fmul_rn(d3, d3));
    }

    // wave reduce in double -> per-block atomic
    double ls = (double)lsum;
    #pragma unroll
    for (int off = 32; off > 0; off >>= 1)
        ls += __shfl_down(ls, off, 64);
    __shared__ double wsum[4];
    const int lane = threadIdx.x & 63;
    const int wid  = threadIdx.x >> 6;
    if (lane == 0) wsum[wid] = ls;
    __syncthreads();
    if (threadIdx.x == 0) {
        double t = ((wsum[0] + wsum[1]) + (wsum[2] + wsum[3]));
        atomicAdd(loss_accum, t);
    }
}

// ---------------------------------------------------------------------------
// Fallback single-kernel (R2 proven path) if ws is too small for partials.
// ---------------------------------------------------------------------------
__global__ __launch_bounds__(256, 2) void vq_main_single(
        const float* __restrict__ in,
        const float* __restrict__ cb,
        const float* __restrict__ cbnorm,
        float* __restrict__ outq,
        double* __restrict__ loss_accum) {
    const int n = blockIdx.x * 256 + threadIdx.x;
    const int b = n >> 15;
    const int s = n & (S_SPATIAL - 1);
    const float* xp = in + (size_t)b * EMB_DIM * S_SPATIAL + s;
    const size_t S = (size_t)S_SPATIAL;
#define LDX(i) const float4 x##i = make_float4(xp[(4*i+0)*S], xp[(4*i+1)*S], \
                                               xp[(4*i+2)*S], xp[(4*i+3)*S])
    LDX(0);  LDX(1);  LDX(2);  LDX(3);  LDX(4);  LDX(5);  LDX(6);  LDX(7);
    LDX(8);  LDX(9);  LDX(10); LDX(11); LDX(12); LDX(13); LDX(14); LDX(15);
#undef LDX
    float xn = 0.f;
#define XN(i) xn = __fadd_rn(xn, __fmul_rn(x##i.x, x##i.x)); \
              xn = __fadd_rn(xn, __fmul_rn(x##i.y, x##i.y)); \
              xn = __fadd_rn(xn, __fmul_rn(x##i.z, x##i.z)); \
              xn = __fadd_rn(xn, __fmul_rn(x##i.w, x##i.w))
    XN(0);  XN(1);  XN(2);  XN(3);  XN(4);  XN(5);  XN(6);  XN(7);
    XN(8);  XN(9);  XN(10); XN(11); XN(12); XN(13); XN(14); XN(15);
#undef XN
    float bestd = INFINITY;
    int bestk = 0;
    for (int k = 0; k < NUM_EMB; ++k) {
        const float4* ev = (const float4*)(cb + (size_t)k * EMB_DIM);
        float a0 = 0.f, a1 = 0.f, a2 = 0.f, a3 = 0.f;
#define DOT(i) { const float4 e = ev[i];            \
                 a0 = fmaf(x##i.x, e.x, a0);        \
                 a1 = fmaf(x##i.y, e.y, a1);        \
                 a2 = fmaf(x##i.z, e.z, a2);        \
                 a3 = fmaf(x##i.w, e.w, a3); }
        DOT(0);  DOT(1);  DOT(2);  DOT(3);  DOT(4);  DOT(5);  DOT(6);  DOT(7);
        DOT(8);  DOT(9);  DOT(10); DOT(11); DOT(12); DOT(13); DOT(14); DOT(15);
#undef DOT
        float dot = __fadd_rn(__fadd_rn(a0, a1), __fadd_rn(a2, a3));
        float d = __fsub_rn(__fadd_rn(xn, cbnorm[k]),
                            __fmul_rn(2.f, dot));
        if (d < bestd) { bestd = d; bestk = k; }
    }
    const float4* q = (const float4*)(cb + (size_t)bestk * EMB_DIM);
    float* op = outq + (size_t)b * EMB_DIM * S_SPATIAL + s;
    float lsum = 0.f;
#define OUTC(i) { const float4 qv = q[i];                                   \
                  op[(4*i+0)*S] = qv.x; op[(4*i+1)*S] = qv.y;               \
                  op[(4*i+2)*S] = qv.z; op[(4*i+3)*S] = qv.w;               \
                  float d0 = __fsub_rn(qv.x, x##i.x);                       \
                  float d1 = __fsub_rn(qv.y, x##i.y);                       \
                  float d2 = __fsub_rn(qv.z, x##i.z);                       \
                  float d3 = __fsub_rn(qv.w, x##i.w);                       \
                  lsum = __fadd_rn(lsum, __fmul_rn(d0, d0));                \
                  lsum = __fadd_rn(lsum, __fmul_rn(d1, d1));                \
                  lsum = __fadd_rn(lsum, __fmul_rn(d2, d2));                \
                  lsum = __fadd_rn(lsum, __fmul_rn(d3, d3)); }
    OUTC(0);  OUTC(1);  OUTC(2);  OUTC(3);  OUTC(4);  OUTC(5);  OUTC(6);  OUTC(7);
    OUTC(8);  OUTC(9);  OUTC(10); OUTC(11); OUTC(12); OUTC(13); OUTC(14); OUTC(15);
#undef OUTC
    double ls = (double)lsum;
    #pragma unroll
    for (int off = 32; off > 0; off >>= 1)
        ls += __shfl_down(ls, off, 64);
    __shared__ double wsum[4];
    const int lane = threadIdx.x & 63;
    const int wid  = threadIdx.x >> 6;
    if (lane == 0) wsum[wid] = ls;
    __syncthreads();
    if (threadIdx.x == 0)
        atomicAdd(loss_accum, (wsum[0] + wsum[1]) + (wsum[2] + wsum[3]));
}

// ---------------------------------------------------------------------------
__global__ void vq_final(const double* __restrict__ loss_accum,
                         float* __restrict__ out0) {
    double m = *loss_accum / (double)((long long)NVEC * EMB_DIM);
    float mf = (float)m;
    out0[0] = __fadd_rn(mf, __fmul_rn(0.25f, mf));
}

extern "C" void kernel_launch(void* const* d_in, const int* in_sizes, int n_in,
                              void* d_out, int out_size, void* d_ws, size_t ws_size,
                              hipStream_t stream) {
    const float* in = (const float*)d_in[0];   // [4, 64, 32, 32, 32]
    const float* cb = (const float*)d_in[1];   // [512, 64]
    float* out = (float*)d_out;                // [0]=loss, [1..]=quantized

    double* loss_accum = (double*)d_ws;
    float* cbnorm = (float*)((char*)d_ws + 256);

    vq_prep<<<4, 128, 0, stream>>>(cb, cbnorm, loss_accum);

    if (ws_size >= (size_t)WS_NEEDED) {
        float* best = (float*)((char*)d_ws + WS_BEST_OFF);
        int*   bkp  = (int*)  ((char*)d_ws + WS_BK_OFF);
        vq_part<<<512 * NCHUNK, 256, 0, stream>>>(in, cb, cbnorm, best, bkp);
        vq_fin <<<512 * 4,      256, 0, stream>>>(in, cb, best, bkp, out + 1,
                                                  loss_accum);
    } else {
        vq_main_single<<<NVEC / 256, 256, 0, stream>>>(in, cb, cbnorm, out + 1,
                                                       loss_accum);
    }
    vq_final<<<1, 1, 0, stream>>>(loss_accum, out);
}